// Round 5
// baseline (6283.711 us; speedup 1.0000x reference)
//
#include <hip/hip_runtime.h>
#include <stdint.h>
#include <stddef.h>

// Persistent 2-layer LSTM decoder, B=1024, H=256, T=512.
// R5: 32 groups x 16 WGs x 256 thr (512 blocks, 2/CU). Group owns 32 chains;
// WG owns 16 hidden units (both layers). Wave = gate tile (i/f/g/o), so
// weights are not duplicated across waves (136 VGPR/wave of B-frags) and
// 2 waves/SIMD fit. Robust XCD grouping: publish XCC_ID + deterministic
// assignment; groups that span XCDs fall back to wbl2/inv-sc1 barriers.
//
// h-buffer layout (per group, layer, parity): chunked f16
//   idx16 = c*32 + m  (chunk c = k/8 in 0..31, row m in 0..31), 16B per chunk
// so an MFMA A-fragment (8 consecutive k for one m) is one 16B chunk.

#define NBLK   512
#define NGROUP 32
#define GWG    16
#define NTHR   256
#define TSTEPS 512
#define MROWS  32

typedef _Float16 half8 __attribute__((ext_vector_type(8)));
typedef float    f32x4 __attribute__((ext_vector_type(4)));

#define OUT_ELEMS   33554432   // 1024*512*64
#define HF_ELEMS    524288     // 2*1024*256
#define HBUF_ELEMS  8192       // 32*256 (f16) per layer/parity
#define GROUP_WS_BYTES 65536   // 4 bufs * 8192 * 2B
#define WS_HBUF_OFF 4096
#define WS_NEEDED   (WS_HBUF_OFF + NGROUP * GROUP_WS_BYTES)  // 2101248 (== R4)

// ws control layout: [0,2048) 32 group ctrs (64B stride); [2048) gridCtr1;
// [2112) gridCtr2; [2176,2688) xccOf bytes.

__device__ __forceinline__ float sigm(float x)   { return 1.0f / (1.0f + __expf(-x)); }
__device__ __forceinline__ float tanh_f(float x) { return 1.0f - 2.0f / (__expf(2.0f * x) + 1.0f); }

// Group barrier. Local (all 16 WGs on one XCD): wg-scope RMW at the XCD L2 +
// L1-only invalidate (R4-proven). Non-local: flush dirty L2 (wbl2 sc1),
// device-scope RMW at IF$, invalidate L2+L1 (R0-proven). zz = asm-opaque zero
// so InstCombine can't fold the poll RMW into an (L1-cacheable, stale) load.
__device__ __forceinline__ void group_barrier(int* ctr, int* phase, int zz, int isLocal) {
  __syncthreads();
  if (threadIdx.x == 0) {
    const int target = GWG * (++(*phase));
    if (isLocal) {
      __hip_atomic_fetch_add(ctr, 1, __ATOMIC_RELEASE, __HIP_MEMORY_SCOPE_WORKGROUP);
      while (__hip_atomic_fetch_add(ctr, zz, __ATOMIC_RELAXED, __HIP_MEMORY_SCOPE_WORKGROUP) < target)
        __builtin_amdgcn_s_sleep(1);
      asm volatile("buffer_inv sc0" ::: "memory");
    } else {
      asm volatile("buffer_wbl2 sc1\n\ts_waitcnt vmcnt(0)" ::: "memory");
      atomicAdd(ctr, 1);  // device scope -> IF$
      while (__hip_atomic_load(ctr, __ATOMIC_RELAXED, __HIP_MEMORY_SCOPE_AGENT) < target)
        __builtin_amdgcn_s_sleep(1);
      asm volatile("buffer_inv sc1" ::: "memory");
    }
  }
  __syncthreads();
}

__device__ __forceinline__ half8 ld_frag(const _Float16* buf, int idx16) {
  return *(const half8*)(buf + (size_t)idx16 * 8);
}

// Packed f16x2 store of (col u, col u+1) for row mh. Even-u lanes only.
__device__ __forceinline__ void store_h_pair(_Float16* hw, int w, int u, int mh,
                                             float lo, float hi) {
  union { _Float16 h[2]; uint32_t u32; } pk;
  pk.h[0] = (_Float16)lo; pk.h[1] = (_Float16)hi;
  const int c = w * 2 + (u >> 3);
  *((uint32_t*)hw + (size_t)(c * MROWS + mh) * 4 + ((u & 7) >> 1)) = pk.u32;
}

__global__ __launch_bounds__(NTHR, 2)
void decoder_kernel(const float* __restrict__ h0in, const float* __restrict__ c0in,
                    const float* __restrict__ Wih0, const float* __restrict__ Whh0,
                    const float* __restrict__ bih0, const float* __restrict__ bhh0,
                    const float* __restrict__ Wih1, const float* __restrict__ Whh1,
                    const float* __restrict__ bih1, const float* __restrict__ bhh1,
                    const float* __restrict__ Wfc,  const float* __restrict__ bfc,
                    float* __restrict__ out, char* __restrict__ ws)
{
  const int tid  = threadIdx.x;
  const int lane = tid & 63;
  const int wv   = tid >> 6;    // wave = gate tile: 0=i, 1=f, 2=g, 3=o
  const int q    = lane >> 4;   // quad
  const int u    = lane & 15;   // unit-in-slice / frag m

  int zz;
  asm volatile("s_mov_b32 %0, 0" : "=s"(zz));

  // ---- robust (xcc-aware) group assignment ----
  __shared__ int s_asn[4];
  __shared__ uint8_t s_x[NBLK];
  {
    uint8_t* xccArr = (uint8_t*)(ws + 2176);
    int* g1 = (int*)(ws + 2048);
    int* g2 = (int*)(ws + 2112);
    if (tid == 0) {
      uint32_t xcc;
      asm volatile("s_getreg_b32 %0, hwreg(HW_REG_XCC_ID)" : "=s"(xcc));
      xcc &= 7;
      __hip_atomic_store(xccArr + blockIdx.x, (uint8_t)xcc,
                         __ATOMIC_RELAXED, __HIP_MEMORY_SCOPE_AGENT);
      atomicAdd(g1, 1);
      while (__hip_atomic_load(g1, __ATOMIC_RELAXED, __HIP_MEMORY_SCOPE_AGENT) < NBLK)
        __builtin_amdgcn_s_sleep(1);
      s_asn[3] = (int)xcc;
    }
    __syncthreads();
    s_x[tid]       = __hip_atomic_load(xccArr + tid,       __ATOMIC_RELAXED, __HIP_MEMORY_SCOPE_AGENT);
    s_x[tid + 256] = __hip_atomic_load(xccArr + tid + 256, __ATOMIC_RELAXED, __HIP_MEMORY_SCOPE_AGENT);
    __syncthreads();
    if (tid == 0) {
      const int xcc = s_asn[3];
      int cnt[8] = {0, 0, 0, 0, 0, 0, 0, 0};
      int rank = 0;
      for (int i = 0; i < NBLK; ++i) {
        const int x = s_x[i];
        cnt[x]++;
        if (x == xcc && i < (int)blockIdx.x) rank++;
      }
      int prefix = 0;
      for (int x = 0; x < xcc; ++x) prefix += cnt[x];
      const int pos = prefix + rank;           // sort by (xcc, blockIdx)
      const int gg = pos >> 4;
      const int local = (gg * 16 >= prefix) && (gg * 16 + 16 <= prefix + cnt[xcc]);
      s_asn[0] = gg; s_asn[1] = pos & 15; s_asn[2] = local;
      atomicAdd(g2, 1);                        // all reads of xccArr done
      while (__hip_atomic_load(g2, __ATOMIC_RELAXED, __HIP_MEMORY_SCOPE_AGENT) < NBLK)
        __builtin_amdgcn_s_sleep(1);
    }
    __syncthreads();
  }
  const int g = s_asn[0];        // group 0..31 (32 chains each)
  const int w = s_asn[1];        // member 0..15 (16-unit slice)
  const int isLocal = s_asn[2];

  int* ctr = (int*)(ws + (size_t)g * 64);
  _Float16* hb_base = (_Float16*)(ws + WS_HBUF_OFF + (size_t)g * GROUP_WS_BYTES);
  auto hbL = [&](int layer, int par) { return hb_base + (size_t)(layer * 2 + par) * HBUF_ELEMS; };

  __shared__ __align__(16) _Float16 xbuf[MROWS * 72];       // bank-pad stride
  __shared__ __align__(16) float    exch[4 * MROWS * 18];   // [tile][row(18-pad)][u]
  __shared__ __align__(16) float    predbuf[MROWS * 68];

  // ---------------- weight fragments (register-resident, f16) ----------------
  // gates = act @ W^T; B-frag: n = u (gate row within tile), k = q*8+j.
  // wave wv owns gate tile base wv*256 (torch order i,f,g,o).
  half8 bL0[10]; half8 bL1[16]; half8 bFC[8];
  float biasL0, biasL1, biasFC;
  {
    const int row = wv * 256 + w * 16 + u;
    biasL0 = bih0[row] + bhh0[row];
    biasL1 = bih1[row] + bhh1[row];
    #pragma unroll
    for (int kt = 0; kt < 10; ++kt) {   // L0: K = 64(x) + 256(h0)
      const int k0 = kt * 32 + q * 8;
      const float* src = (kt < 2) ? (Wih0 + (size_t)row * 64 + k0)
                                  : (Whh0 + (size_t)row * 256 + (k0 - 64));
      half8 v;
      #pragma unroll
      for (int j = 0; j < 8; ++j) v[j] = (_Float16)src[j];
      bL0[kt] = v;
    }
    #pragma unroll
    for (int kt = 0; kt < 16; ++kt) {   // L1: K = 256(h0new) + 256(h1)
      const int k0 = kt * 32 + q * 8;
      const float* src = (kt < 8) ? (Wih1 + (size_t)row * 256 + k0)
                                  : (Whh1 + (size_t)row * 256 + (k0 - 256));
      half8 v;
      #pragma unroll
      for (int j = 0; j < 8; ++j) v[j] = (_Float16)src[j];
      bL1[kt] = v;
    }
    const int rowF = wv * 16 + u;       // FC output col
    biasFC = bfc[rowF];
    #pragma unroll
    for (int kt = 0; kt < 8; ++kt) {
      const float* src = Wfc + (size_t)rowF * 256 + kt * 32 + q * 8;
      half8 v;
      #pragma unroll
      for (int j = 0; j < 8; ++j) v[j] = (_Float16)src[j];
      bFC[kt] = v;
    }
  }

  // ---------------- state init ----------------
  float c0st[2][4], c1st[2][4], h0sv[2][4], h1sv[2][4];
  #pragma unroll
  for (int mt = 0; mt < 2; ++mt)
    #pragma unroll
    for (int r = 0; r < 4; ++r) { c0st[mt][r] = 0; c1st[mt][r] = 0; h0sv[mt][r] = 0; h1sv[mt][r] = 0; }
  if (wv == 3) {  // o-wave owns c-state in D-frag layout: row = mt*16+q*4+r, col = w*16+u
    #pragma unroll
    for (int mt = 0; mt < 2; ++mt)
      #pragma unroll
      for (int r = 0; r < 4; ++r) {
        const int ch = g * MROWS + mt * 16 + q * 4 + r;
        c0st[mt][r] = c0in[(size_t)ch * 256 + w * 16 + u];
        c1st[mt][r] = c0in[262144 + (size_t)ch * 256 + w * 16 + u];
      }
  }
  if (tid < 128) {  // initial h -> parity-1 chunked buffers (own 16-unit slice)
    const int gi = tid * 4;
    const int e0 = gi & 7;              // 0 or 4
    const int m  = (gi >> 3) & 31;
    const int cc = gi >> 8;             // 0 or 1
    const int c  = w * 2 + cc;
    const int col = c * 8 + e0;
    #pragma unroll
    for (int l = 0; l < 2; ++l) {
      const float* s = h0in + (size_t)l * 262144 + (size_t)(g * MROWS + m) * 256 + col;
      union { _Float16 h[4]; uint64_t u64; } pk;
      #pragma unroll
      for (int j = 0; j < 4; ++j) pk.h[j] = (_Float16)s[j];
      *((uint64_t*)hbL(l, 1) + ((size_t)(c * MROWS + m) * 2 + (e0 >> 2))) = pk.u64;
    }
  }
  for (int i = tid; i < MROWS * 64; i += NTHR) {  // x0: zeros, col 61 = 1 (SOS)
    const int row = i >> 6, col = i & 63;
    xbuf[row * 72 + col] = (col == 61) ? (_Float16)1.0f : (_Float16)0.0f;
  }

  int phase = 0;
  group_barrier(ctr, &phase, zz, isLocal);

  // ---------------- time loop ----------------
  for (int t = 0; t < TSTEPS; ++t) {
    // ======== Layer 0: gates = [x | h0_prev] @ W^T ========
    {
      const _Float16* h0rd = hbL(0, (t + 1) & 1);
      f32x4 acc[2];
      #pragma unroll
      for (int mt = 0; mt < 2; ++mt) {
        f32x4 v; v[0] = biasL0; v[1] = biasL0; v[2] = biasL0; v[3] = biasL0;
        acc[mt] = v;
      }
      #pragma unroll
      for (int kt = 0; kt < 10; ++kt) {
        half8 a[2];
        #pragma unroll
        for (int mt = 0; mt < 2; ++mt) {
          const int m = mt * 16 + u;
          if (kt < 2) a[mt] = *(const half8*)(xbuf + m * 72 + kt * 32 + q * 8);
          else        a[mt] = ld_frag(h0rd, (kt * 4 - 8 + q) * MROWS + m);
        }
        #pragma unroll
        for (int mt = 0; mt < 2; ++mt)
          acc[mt] = __builtin_amdgcn_mfma_f32_16x16x32_f16(a[mt], bL0[kt], acc[mt], 0, 0, 0);
      }
      if (wv < 3) {  // publish activated tile: sigm(i), sigm(f), tanh(g)
        #pragma unroll
        for (int mt = 0; mt < 2; ++mt)
          #pragma unroll
          for (int r = 0; r < 4; ++r) {
            const int row = mt * 16 + q * 4 + r;
            exch[wv * (MROWS * 18) + row * 18 + u] =
                (wv == 2) ? tanh_f(acc[mt][r]) : sigm(acc[mt][r]);
          }
      }
      __syncthreads();
      if (wv == 3) {  // cell update (holds o-tile + c-state)
        _Float16* h0wr = hbL(0, t & 1);
        float hv[2][4];
        #pragma unroll
        for (int mt = 0; mt < 2; ++mt)
          #pragma unroll
          for (int r = 0; r < 4; ++r) {
            const int row = mt * 16 + q * 4 + r;
            const float si = exch[row * 18 + u];
            const float sf = exch[(MROWS * 18) + row * 18 + u];
            const float tg = exch[2 * (MROWS * 18) + row * 18 + u];
            const float cn = sf * c0st[mt][r] + si * tg;
            c0st[mt][r] = cn;
            const float hh = sigm(acc[mt][r]) * tanh_f(cn);
            h0sv[mt][r] = hh; hv[mt][r] = hh;
          }
        #pragma unroll
        for (int mt = 0; mt < 2; ++mt)
          #pragma unroll
          for (int r = 0; r < 4; ++r) {
            const float other = __shfl_xor(hv[mt][r], 1);
            if (!(u & 1))
              store_h_pair(h0wr, w, u, mt * 16 + q * 4 + r, hv[mt][r], other);
          }
      }
    }
    group_barrier(ctr, &phase, zz, isLocal);

    // ======== Layer 1: gates = [h0_new | h1_prev] @ W^T ========
    {
      const _Float16* h0nw = hbL(0, t & 1);
      const _Float16* h1rd = hbL(1, (t + 1) & 1);
      f32x4 acc[2];
      #pragma unroll
      for (int mt = 0; mt < 2; ++mt) {
        f32x4 v; v[0] = biasL1; v[1] = biasL1; v[2] = biasL1; v[3] = biasL1;
        acc[mt] = v;
      }
      #pragma unroll
      for (int kt = 0; kt < 16; ++kt) {
        half8 a[2];
        #pragma unroll
        for (int mt = 0; mt < 2; ++mt) {
          const int m = mt * 16 + u;
          if (kt < 8) a[mt] = ld_frag(h0nw, (kt * 4 + q) * MROWS + m);
          else        a[mt] = ld_frag(h1rd, ((kt - 8) * 4 + q) * MROWS + m);
        }
        #pragma unroll
        for (int mt = 0; mt < 2; ++mt)
          acc[mt] = __builtin_amdgcn_mfma_f32_16x16x32_f16(a[mt], bL1[kt], acc[mt], 0, 0, 0);
      }
      if (wv < 3) {
        #pragma unroll
        for (int mt = 0; mt < 2; ++mt)
          #pragma unroll
          for (int r = 0; r < 4; ++r) {
            const int row = mt * 16 + q * 4 + r;
            exch[wv * (MROWS * 18) + row * 18 + u] =
                (wv == 2) ? tanh_f(acc[mt][r]) : sigm(acc[mt][r]);
          }
      }
      __syncthreads();
      if (wv == 3) {
        _Float16* h1wr = hbL(1, t & 1);
        float hv[2][4];
        #pragma unroll
        for (int mt = 0; mt < 2; ++mt)
          #pragma unroll
          for (int r = 0; r < 4; ++r) {
            const int row = mt * 16 + q * 4 + r;
            const float si = exch[row * 18 + u];
            const float sf = exch[(MROWS * 18) + row * 18 + u];
            const float tg = exch[2 * (MROWS * 18) + row * 18 + u];
            const float cn = sf * c1st[mt][r] + si * tg;
            c1st[mt][r] = cn;
            const float hh = sigm(acc[mt][r]) * tanh_f(cn);
            h1sv[mt][r] = hh; hv[mt][r] = hh;
          }
        #pragma unroll
        for (int mt = 0; mt < 2; ++mt)
          #pragma unroll
          for (int r = 0; r < 4; ++r) {
            const float other = __shfl_xor(hv[mt][r], 1);
            if (!(u & 1))
              store_h_pair(h1wr, w, u, mt * 16 + q * 4 + r, hv[mt][r], other);
          }
      }
    }
    group_barrier(ctr, &phase, zz, isLocal);

    // ======== FC + log_softmax (redundant per WG; each wave one 16-col tile) ========
    {
      const _Float16* h1nw = hbL(1, t & 1);
      f32x4 acc[2];
      #pragma unroll
      for (int mt = 0; mt < 2; ++mt) {
        f32x4 v; v[0] = biasFC; v[1] = biasFC; v[2] = biasFC; v[3] = biasFC;
        acc[mt] = v;
      }
      #pragma unroll
      for (int kt = 0; kt < 8; ++kt) {
        half8 a[2];
        #pragma unroll
        for (int mt = 0; mt < 2; ++mt) {
          const int m = mt * 16 + u;
          a[mt] = ld_frag(h1nw, (kt * 4 + q) * MROWS + m);
        }
        #pragma unroll
        for (int mt = 0; mt < 2; ++mt)
          acc[mt] = __builtin_amdgcn_mfma_f32_16x16x32_f16(a[mt], bFC[kt], acc[mt], 0, 0, 0);
      }
      #pragma unroll
      for (int mt = 0; mt < 2; ++mt)
        #pragma unroll
        for (int r = 0; r < 4; ++r)
          predbuf[(mt * 16 + q * 4 + r) * 68 + wv * 16 + u] = acc[mt][r];
    }
    __syncthreads();
    if (tid < 128) {
      const int row = tid >> 2;   // group-local chain 0..31
      const int cg  = tid & 3;    // 16-col group
      const float* pr = predbuf + row * 68 + cg * 16;
      float p[16];
      #pragma unroll
      for (int j = 0; j < 16; ++j) p[j] = pr[j];
      float mx = -3.0e38f;
      #pragma unroll
      for (int j = 0; j < 16; ++j)
        if (!(cg == 3 && j == 15)) mx = fmaxf(mx, p[j]);   // exclude col 63 (dur)
      mx = fmaxf(mx, __shfl_xor(mx, 1));
      mx = fmaxf(mx, __shfl_xor(mx, 2));
      float sm = 0.0f;
      #pragma unroll
      for (int j = 0; j < 16; ++j)
        if (!(cg == 3 && j == 15)) sm += __expf(p[j] - mx);
      sm += __shfl_xor(sm, 1);
      sm += __shfl_xor(sm, 2);
      const float lz = mx + __logf(sm);
      const bool ows = ((row >> 1) == w);   // each WG owns 2 of the 32 rows
      float* dst = out + ((size_t)(g * MROWS + row) * TSTEPS + t) * 64 + cg * 16;
      _Float16* xw = xbuf + row * 72 + cg * 16;
      #pragma unroll
      for (int j = 0; j < 16; ++j) {
        const float val = (cg == 3 && j == 15) ? sigm(p[15]) : (p[j] - lz);
        xw[j] = (_Float16)val;                 // feedback x = out (f16)
        if (ows) dst[j] = val;
      }
    }
    __syncthreads();
  }

  // ---------------- final h_f, c_f ----------------
  if (wv == 3) {
    float* hf = out + OUT_ELEMS;
    float* cf = out + OUT_ELEMS + HF_ELEMS;
    #pragma unroll
    for (int mt = 0; mt < 2; ++mt)
      #pragma unroll
      for (int r = 0; r < 4; ++r) {
        const int ch = g * MROWS + mt * 16 + q * 4 + r;
        const size_t idx = (size_t)ch * 256 + w * 16 + u;
        hf[idx] = h0sv[mt][r];
        hf[262144 + idx] = h1sv[mt][r];
        cf[idx] = c0st[mt][r];
        cf[262144 + idx] = c1st[mt][r];
      }
  }
}

extern "C" void kernel_launch(void* const* d_in, const int* in_sizes, int n_in,
                              void* d_out, int out_size, void* d_ws, size_t ws_size,
                              hipStream_t stream) {
  (void)in_sizes; (void)n_in; (void)out_size;
  if (ws_size < (size_t)WS_NEEDED) return;

  const float* h0   = (const float*)d_in[1];
  const float* c0   = (const float*)d_in[2];
  const float* Wih0 = (const float*)d_in[3];
  const float* Whh0 = (const float*)d_in[4];
  const float* bih0 = (const float*)d_in[5];
  const float* bhh0 = (const float*)d_in[6];
  const float* Wih1 = (const float*)d_in[7];
  const float* Whh1 = (const float*)d_in[8];
  const float* bih1 = (const float*)d_in[9];
  const float* bhh1 = (const float*)d_in[10];
  const float* Wfc  = (const float*)d_in[11];
  const float* bfc  = (const float*)d_in[12];
  float* outp = (float*)d_out;
  char*  wsp  = (char*)d_ws;

  // zero control region (ctrs, grid counters, xccOf); ws re-poisoned each call
  hipMemsetAsync(d_ws, 0, WS_HBUF_OFF, stream);

  void* args[] = { &h0, &c0, &Wih0, &Whh0, &bih0, &bhh0, &Wih1, &Whh1,
                   &bih1, &bhh1, &Wfc, &bfc, &outp, &wsp };
  hipError_t e = hipLaunchCooperativeKernel((const void*)decoder_kernel,
                                            dim3(NBLK), dim3(NTHR),
                                            args, 0u, stream);
  if (e != hipSuccess) {
    // fallback: plain launch (512 blocks at 2/CU fit and are co-resident)
    decoder_kernel<<<dim3(NBLK), dim3(NTHR), 0, stream>>>(
        h0, c0, Wih0, Whh0, bih0, bhh0, Wih1, Whh1, bih1, bhh1, Wfc, bfc, outp, wsp);
  }
}